// Round 1
// baseline (351.333 us; speedup 1.0000x reference)
//
#include <hip/hip_runtime.h>
#include <hip/hip_bf16.h>

#define D_MODEL 768
#define NH 12
#define DHd 64
#define NB 2
#define SL 4096
#define BLr (NB*SL)      // 8192 rows
#define N3 (3*D_MODEL)   // 2304

typedef __bf16 bf16x8 __attribute__((ext_vector_type(8)));
typedef float f32x4 __attribute__((ext_vector_type(4)));

__device__ __forceinline__ unsigned short f2bf(float f) {
  unsigned int u = __float_as_uint(f);
  u = (u + 0x7FFFu + ((u >> 16) & 1u)) >> 16;   // round-to-nearest-even
  return (unsigned short)u;
}

// ---------------- prep kernels ----------------
__global__ __launch_bounds__(256) void cast_f32_bf16(const float* __restrict__ in,
                                                     unsigned short* __restrict__ out, int n4) {
  int i = blockIdx.x * 256 + threadIdx.x;
  if (i >= n4) return;
  float4 v = reinterpret_cast<const float4*>(in)[i];
  ushort4 o;
  o.x = f2bf(v.x); o.y = f2bf(v.y); o.z = f2bf(v.z); o.w = f2bf(v.w);
  reinterpret_cast<ushort4*>(out)[i] = o;
}

// out[c][r] = bf16(in[r][c]); R,C multiples of 32
__global__ __launch_bounds__(256) void transpose_cast(const float* __restrict__ in,
                                                      unsigned short* __restrict__ out,
                                                      int R, int C) {
  __shared__ float t[32][33];
  int c0 = blockIdx.x * 32, r0 = blockIdx.y * 32;
  int tx = threadIdx.x & 31, ty = threadIdx.x >> 5;   // 32 x 8
  #pragma unroll
  for (int i = 0; i < 32; i += 8) t[ty + i][tx] = in[(size_t)(r0 + ty + i) * C + c0 + tx];
  __syncthreads();
  #pragma unroll
  for (int i = 0; i < 32; i += 8) out[(size_t)(c0 + ty + i) * R + r0 + tx] = f2bf(t[tx][ty + i]);
}

// ---------------- bf16 GEMM: C = A(MxK) * Bt(NxK)^T + bias ----------------
// MODE 0: QKV epilogue -> scatter Q(scaled)/K to [b,h,l,d], V to [b,h,d,l]
// MODE 1: fp32 epilogue -> Out[row*N+col]
template<int MODE>
__global__ __launch_bounds__(256) void gemm_bf16(const unsigned short* __restrict__ A,
                                                 const unsigned short* __restrict__ Bt,
                                                 const float* __restrict__ bias,
                                                 void* __restrict__ o0, void* __restrict__ o1,
                                                 void* __restrict__ o2,
                                                 int M, int N, int Kdim) {
  constexpr int LDT = 40;                       // 32 + 8 pad (bank-conflict-free, 16B aligned)
  __shared__ unsigned short As[128 * LDT];
  __shared__ unsigned short Bs[128 * LDT];
  const int tid = threadIdx.x;
  const int lane = tid & 63, wave = tid >> 6;
  const int tm = blockIdx.x * 128, tn = blockIdx.y * 128;
  const int wm = (wave >> 1) * 64, wn = (wave & 1) * 64;  // 2x2 waves of 64x64
  const int fr = lane & 15, fk8 = (lane >> 4) * 8;
  const int srow = tid >> 2, scol = (tid & 3) * 8;        // staging: 64 rows x 4 chunks

  f32x4 acc[4][4] = {};

  const unsigned short* Arow0 = A + (size_t)(tm + srow) * Kdim + scol;
  const unsigned short* Arow1 = A + (size_t)(tm + 64 + srow) * Kdim + scol;
  const unsigned short* Brow0 = Bt + (size_t)(tn + srow) * Kdim + scol;
  const unsigned short* Brow1 = Bt + (size_t)(tn + 64 + srow) * Kdim + scol;

  for (int k0 = 0; k0 < Kdim; k0 += 32) {
    ulonglong2 a0 = *(const ulonglong2*)(Arow0 + k0);
    ulonglong2 a1 = *(const ulonglong2*)(Arow1 + k0);
    ulonglong2 b0 = *(const ulonglong2*)(Brow0 + k0);
    ulonglong2 b1 = *(const ulonglong2*)(Brow1 + k0);
    __syncthreads();
    *(ulonglong2*)(As + srow * LDT + scol) = a0;
    *(ulonglong2*)(As + (64 + srow) * LDT + scol) = a1;
    *(ulonglong2*)(Bs + srow * LDT + scol) = b0;
    *(ulonglong2*)(Bs + (64 + srow) * LDT + scol) = b1;
    __syncthreads();

    bf16x8 af[4], bfr[4];
    #pragma unroll
    for (int i = 0; i < 4; i++) {
      af[i]  = *(const bf16x8*)(As + (wm + i * 16 + fr) * LDT + fk8);
      bfr[i] = *(const bf16x8*)(Bs + (wn + i * 16 + fr) * LDT + fk8);
    }
    #pragma unroll
    for (int i = 0; i < 4; i++)
      #pragma unroll
      for (int j = 0; j < 4; j++)
        acc[i][j] = __builtin_amdgcn_mfma_f32_16x16x32_bf16(af[i], bfr[j], acc[i][j], 0, 0, 0);
  }

  const int fq = (lane >> 4) * 4;
  if constexpr (MODE == 0) {
    unsigned short* Qb  = (unsigned short*)o0;
    unsigned short* Kb  = (unsigned short*)o1;
    unsigned short* Vtb = (unsigned short*)o2;
    #pragma unroll
    for (int j = 0; j < 4; j++) {
      int col = tn + wn + j * 16 + fr;
      float bv = bias[col];
      int which = col / D_MODEL;
      int hd = col % D_MODEL;
      int h = hd >> 6, d = hd & 63;
      #pragma unroll
      for (int i = 0; i < 4; i++) {
        #pragma unroll
        for (int r = 0; r < 4; r++) {
          int row = tm + wm + i * 16 + fq + r;
          int b = row >> 12, l = row & 4095;
          float v = acc[i][j][r] + bv;
          size_t hb = (size_t)b * NH + h;
          if (which == 0)      Qb[(hb * SL + l) * DHd + d] = f2bf(v * 0.125f);
          else if (which == 1) Kb[(hb * SL + l) * DHd + d] = f2bf(v);
          else                 Vtb[(hb * DHd + d) * SL + l] = f2bf(v);
        }
      }
    }
  } else {
    float* Out = (float*)o0;
    #pragma unroll
    for (int i = 0; i < 4; i++)
      #pragma unroll
      for (int j = 0; j < 4; j++) {
        int col = tn + wn + j * 16 + fr;
        float bv = bias[col];
        #pragma unroll
        for (int r = 0; r < 4; r++) {
          int row = tm + wm + i * 16 + fq + r;
          Out[(size_t)row * N + col] = acc[i][j][r] + bv;
        }
      }
  }
}

// ---------------- flash attention ----------------
// grid: (SL/64, NB*NH); block 256 (4 waves x 16 q-rows). K chunks of 64.
// Q pre-scaled by 1/8. V is stored transposed [bh][d][L].
__global__ __launch_bounds__(256) void attn_fwd(const unsigned short* __restrict__ Q,
                                                const unsigned short* __restrict__ K,
                                                const unsigned short* __restrict__ V,
                                                unsigned short* __restrict__ O) {
  const int bh = blockIdx.y;
  const int q0 = blockIdx.x * 64;
  const int tid = threadIdx.x;
  const int wave = tid >> 6, lane = tid & 63;
  const int fr = lane & 15, fk = lane >> 4;

  const unsigned short* Qbh = Q + (size_t)bh * SL * DHd;
  const unsigned short* Kbh = K + (size_t)bh * SL * DHd;
  const unsigned short* Vbh = V + (size_t)bh * DHd * SL;

  __shared__ unsigned short Ks[64 * 64];   // [kv][d]  swizzled rows of 128B
  __shared__ unsigned short Vs[64 * 64];   // [d][kv]  swizzled
  __shared__ unsigned short Ps[4][16 * 64];// per-wave P, swizzled

  const unsigned short* qrow = Qbh + (size_t)(q0 + wave * 16 + fr) * DHd + fk * 8;
  bf16x8 qf0 = *(const bf16x8*)qrow;
  bf16x8 qf1 = *(const bf16x8*)(qrow + 32);

  f32x4 oacc[4] = {};
  float m_i[4], l_i[4];
  #pragma unroll
  for (int r = 0; r < 4; r++) { m_i[r] = -1e30f; l_i[r] = 0.f; }

  char* ksb = (char*)Ks;
  char* vsb = (char*)Vs;
  char* psb = (char*)(&Ps[wave][0]);
  const int srow = tid >> 3;          // 0..31
  const int sc = (tid & 7) * 16;      // byte col within 128B row

  for (int k0 = 0; k0 <= q0; k0 += 64) {
    ulonglong2 kva = *(const ulonglong2*)((const char*)(Kbh + (size_t)(k0 + srow) * DHd) + sc);
    ulonglong2 kvb = *(const ulonglong2*)((const char*)(Kbh + (size_t)(k0 + srow + 32) * DHd) + sc);
    ulonglong2 vva = *(const ulonglong2*)((const char*)(Vbh + (size_t)srow * SL + k0) + sc);
    ulonglong2 vvb = *(const ulonglong2*)((const char*)(Vbh + (size_t)(srow + 32) * SL + k0) + sc);
    __syncthreads();
    *(ulonglong2*)(ksb + srow * 128 + (sc ^ ((srow & 7) << 4))) = kva;
    *(ulonglong2*)(ksb + (srow + 32) * 128 + (sc ^ ((srow & 7) << 4))) = kvb;
    *(ulonglong2*)(vsb + srow * 128 + (sc ^ ((srow & 7) << 4))) = vva;
    *(ulonglong2*)(vsb + (srow + 32) * 128 + (sc ^ ((srow & 7) << 4))) = vvb;
    __syncthreads();

    // S = Q K^T   (S frag n: rows fk*4+r, cols n*16+fr)
    f32x4 s[4] = {};
    #pragma unroll
    for (int n = 0; n < 4; n++) {
      int r = n * 16 + fr;
      const char* kbase = ksb + r * 128;
      int swz = (r & 7) << 4;
      bf16x8 b0 = *(const bf16x8*)(kbase + ((fk * 16) ^ swz));
      bf16x8 b1 = *(const bf16x8*)(kbase + ((64 + fk * 16) ^ swz));
      s[n] = __builtin_amdgcn_mfma_f32_16x16x32_bf16(qf0, b0, s[n], 0, 0, 0);
      s[n] = __builtin_amdgcn_mfma_f32_16x16x32_bf16(qf1, b1, s[n], 0, 0, 0);
    }

    if (k0 == q0) {   // causal mask, diagonal chunk only
      #pragma unroll
      for (int n = 0; n < 4; n++)
        #pragma unroll
        for (int r = 0; r < 4; r++) {
          int qr = wave * 16 + fk * 4 + r;
          int kc = n * 16 + fr;
          if (kc > qr) s[n][r] = -1e30f;
        }
    }

    // online softmax (rows spread over 16 lanes sharing fk)
    float newm[4], scale[4];
    #pragma unroll
    for (int r = 0; r < 4; r++) {
      float m0 = fmaxf(fmaxf(s[0][r], s[1][r]), fmaxf(s[2][r], s[3][r]));
      m0 = fmaxf(m0, __shfl_xor(m0, 1));
      m0 = fmaxf(m0, __shfl_xor(m0, 2));
      m0 = fmaxf(m0, __shfl_xor(m0, 4));
      m0 = fmaxf(m0, __shfl_xor(m0, 8));
      newm[r] = fmaxf(m_i[r], m0);
      scale[r] = __expf(m_i[r] - newm[r]);
      m_i[r] = newm[r];
    }
    #pragma unroll
    for (int n = 0; n < 4; n++)
      #pragma unroll
      for (int r = 0; r < 4; r++)
        s[n][r] = __expf(s[n][r] - newm[r]);
    #pragma unroll
    for (int r = 0; r < 4; r++) {
      float t = s[0][r] + s[1][r] + s[2][r] + s[3][r];
      t += __shfl_xor(t, 1);
      t += __shfl_xor(t, 2);
      t += __shfl_xor(t, 4);
      t += __shfl_xor(t, 8);
      l_i[r] = l_i[r] * scale[r] + t;
    }
    #pragma unroll
    for (int n = 0; n < 4; n++)
      #pragma unroll
      for (int r = 0; r < 4; r++)
        oacc[n][r] *= scale[r];

    // P -> wave-private LDS (bf16, swizzled): layout convert S-frag -> A-frag
    #pragma unroll
    for (int n = 0; n < 4; n++)
      #pragma unroll
      for (int r = 0; r < 4; r++) {
        int row = fk * 4 + r;
        int colb = (n * 16 + fr) * 2;
        *(unsigned short*)(psb + row * 128 + (colb ^ ((row & 7) << 4))) = f2bf(s[n][r]);
      }
    asm volatile("" ::: "memory");   // compiler fence: DS ops in-order per wave

    // O += P @ V
    #pragma unroll
    for (int kk = 0; kk < 2; kk++) {
      int pcb = kk * 64 + fk * 16;
      bf16x8 pa = *(const bf16x8*)(psb + fr * 128 + (pcb ^ ((fr & 7) << 4)));
      #pragma unroll
      for (int n = 0; n < 4; n++) {
        int vr = n * 16 + fr;
        int vcb = kk * 64 + fk * 16;
        bf16x8 vb = *(const bf16x8*)(vsb + vr * 128 + (vcb ^ ((vr & 7) << 4)));
        oacc[n] = __builtin_amdgcn_mfma_f32_16x16x32_bf16(pa, vb, oacc[n], 0, 0, 0);
      }
    }
  }

  const int b = bh / NH, h = bh % NH;
  float inv[4];
  #pragma unroll
  for (int r = 0; r < 4; r++) inv[r] = 1.0f / l_i[r];
  #pragma unroll
  for (int n = 0; n < 4; n++)
    #pragma unroll
    for (int r = 0; r < 4; r++) {
      int q = q0 + wave * 16 + fk * 4 + r;
      int d = n * 16 + fr;
      O[((size_t)b * SL + q) * D_MODEL + h * DHd + d] = f2bf(oacc[n][r] * inv[r]);
    }
}

// ---------------- launch ----------------
extern "C" void kernel_launch(void* const* d_in, const int* in_sizes, int n_in,
                              void* d_out, int out_size, void* d_ws, size_t ws_size,
                              hipStream_t stream) {
  (void)in_sizes; (void)n_in; (void)out_size; (void)ws_size;
  const float* x     = (const float*)d_in[0];
  const float* w_qkv = (const float*)d_in[1];
  const float* b_qkv = (const float*)d_in[2];
  const float* w_out = (const float*)d_in[3];
  const float* b_out = (const float*)d_in[4];
  float* out = (float*)d_out;

  unsigned short* p = (unsigned short*)d_ws;
  unsigned short* xb    = p; p += (size_t)BLr * D_MODEL;       // x in bf16
  unsigned short* wqkvT = p; p += (size_t)N3 * D_MODEL;        // w_qkv^T bf16 [2304][768]
  unsigned short* woutT = p; p += (size_t)D_MODEL * D_MODEL;   // w_out^T bf16 [768][768]
  unsigned short* Qb    = p; p += (size_t)NB * NH * SL * DHd;  // [b,h,l,d] (pre-scaled)
  unsigned short* Kb    = p; p += (size_t)NB * NH * SL * DHd;  // [b,h,l,d]
  unsigned short* Vtb   = p; p += (size_t)NB * NH * SL * DHd;  // [b,h,d,l]
  unsigned short* Ob    = p;                                   // [b*l][768] bf16

  cast_f32_bf16<<<(BLr * D_MODEL / 4 + 255) / 256, 256, 0, stream>>>(x, xb, BLr * D_MODEL / 4);
  transpose_cast<<<dim3(N3 / 32, D_MODEL / 32), 256, 0, stream>>>(w_qkv, wqkvT, D_MODEL, N3);
  transpose_cast<<<dim3(D_MODEL / 32, D_MODEL / 32), 256, 0, stream>>>(w_out, woutT, D_MODEL, D_MODEL);
  gemm_bf16<0><<<dim3(BLr / 128, N3 / 128), 256, 0, stream>>>(xb, wqkvT, b_qkv, Qb, Kb, Vtb,
                                                              BLr, N3, D_MODEL);
  attn_fwd<<<dim3(SL / 64, NB * NH), 256, 0, stream>>>(Qb, Kb, Vtb, Ob);
  gemm_bf16<1><<<dim3(BLr / 128, D_MODEL / 128), 256, 0, stream>>>(Ob, woutT, b_out, out,
                                                                   nullptr, nullptr,
                                                                   BLr, D_MODEL, D_MODEL);
}

// Round 2
// 257.071 us; speedup vs baseline: 1.3667x; 1.3667x over previous
//
#include <hip/hip_runtime.h>
#include <hip/hip_bf16.h>

#define D_MODEL 768
#define NH 12
#define DHd 64
#define NB 2
#define SL 4096
#define BLr (NB*SL)      // 8192 rows
#define N3 (3*D_MODEL)   // 2304
#define QSCALE 0.18033688011112042f   // 0.125 * log2(e): softmax done in log2 domain

typedef __bf16 bf16x8 __attribute__((ext_vector_type(8)));
typedef float f32x4 __attribute__((ext_vector_type(4)));

__device__ __forceinline__ unsigned short f2bf(float f) {
  unsigned int u = __float_as_uint(f);
  u = (u + 0x7FFFu + ((u >> 16) & 1u)) >> 16;   // round-to-nearest-even
  return (unsigned short)u;
}
__device__ __forceinline__ unsigned short bfc(float f) {   // compiler-lowered cast
  __bf16 h = (__bf16)f;
  return __builtin_bit_cast(unsigned short, h);
}
__device__ __forceinline__ float fexp2(float x) {          // raw v_exp_f32 (exp2)
  float r; asm("v_exp_f32 %0, %1" : "=v"(r) : "v"(x)); return r;
}

// ---------------- prep kernels ----------------
__global__ __launch_bounds__(256) void cast_f32_bf16(const float* __restrict__ in,
                                                     unsigned short* __restrict__ out, int n4) {
  int i = blockIdx.x * 256 + threadIdx.x;
  if (i >= n4) return;
  float4 v = reinterpret_cast<const float4*>(in)[i];
  ushort4 o;
  o.x = f2bf(v.x); o.y = f2bf(v.y); o.z = f2bf(v.z); o.w = f2bf(v.w);
  reinterpret_cast<ushort4*>(out)[i] = o;
}

// out[c][r] = bf16(in[r][c]); R,C multiples of 32
__global__ __launch_bounds__(256) void transpose_cast(const float* __restrict__ in,
                                                      unsigned short* __restrict__ out,
                                                      int R, int C) {
  __shared__ float t[32][33];
  int c0 = blockIdx.x * 32, r0 = blockIdx.y * 32;
  int tx = threadIdx.x & 31, ty = threadIdx.x >> 5;   // 32 x 8
  #pragma unroll
  for (int i = 0; i < 32; i += 8) t[ty + i][tx] = in[(size_t)(r0 + ty + i) * C + c0 + tx];
  __syncthreads();
  #pragma unroll
  for (int i = 0; i < 32; i += 8) out[(size_t)(c0 + ty + i) * R + r0 + tx] = f2bf(t[tx][ty + i]);
}

// ---------------- bf16 GEMM: C = A(MxK) * Bt(NxK)^T + bias ----------------
template<int MODE>
__global__ __launch_bounds__(256) void gemm_bf16(const unsigned short* __restrict__ A,
                                                 const unsigned short* __restrict__ Bt,
                                                 const float* __restrict__ bias,
                                                 void* __restrict__ o0, void* __restrict__ o1,
                                                 void* __restrict__ o2,
                                                 int M, int N, int Kdim) {
  constexpr int LDT = 40;
  __shared__ unsigned short As[128 * LDT];
  __shared__ unsigned short Bs[128 * LDT];
  const int tid = threadIdx.x;
  const int lane = tid & 63, wave = tid >> 6;
  const int tm = blockIdx.x * 128, tn = blockIdx.y * 128;
  const int wm = (wave >> 1) * 64, wn = (wave & 1) * 64;
  const int fr = lane & 15, fk8 = (lane >> 4) * 8;
  const int srow = tid >> 2, scol = (tid & 3) * 8;

  f32x4 acc[4][4] = {};

  const unsigned short* Arow0 = A + (size_t)(tm + srow) * Kdim + scol;
  const unsigned short* Arow1 = A + (size_t)(tm + 64 + srow) * Kdim + scol;
  const unsigned short* Brow0 = Bt + (size_t)(tn + srow) * Kdim + scol;
  const unsigned short* Brow1 = Bt + (size_t)(tn + 64 + srow) * Kdim + scol;

  for (int k0 = 0; k0 < Kdim; k0 += 32) {
    ulonglong2 a0 = *(const ulonglong2*)(Arow0 + k0);
    ulonglong2 a1 = *(const ulonglong2*)(Arow1 + k0);
    ulonglong2 b0 = *(const ulonglong2*)(Brow0 + k0);
    ulonglong2 b1 = *(const ulonglong2*)(Brow1 + k0);
    __syncthreads();
    *(ulonglong2*)(As + srow * LDT + scol) = a0;
    *(ulonglong2*)(As + (64 + srow) * LDT + scol) = a1;
    *(ulonglong2*)(Bs + srow * LDT + scol) = b0;
    *(ulonglong2*)(Bs + (64 + srow) * LDT + scol) = b1;
    __syncthreads();

    bf16x8 af[4], bfr[4];
    #pragma unroll
    for (int i = 0; i < 4; i++) {
      af[i]  = *(const bf16x8*)(As + (wm + i * 16 + fr) * LDT + fk8);
      bfr[i] = *(const bf16x8*)(Bs + (wn + i * 16 + fr) * LDT + fk8);
    }
    #pragma unroll
    for (int i = 0; i < 4; i++)
      #pragma unroll
      for (int j = 0; j < 4; j++)
        acc[i][j] = __builtin_amdgcn_mfma_f32_16x16x32_bf16(af[i], bfr[j], acc[i][j], 0, 0, 0);
  }

  const int fq = (lane >> 4) * 4;
  if constexpr (MODE == 0) {
    unsigned short* Qb  = (unsigned short*)o0;
    unsigned short* Kb  = (unsigned short*)o1;
    unsigned short* Vtb = (unsigned short*)o2;
    #pragma unroll
    for (int j = 0; j < 4; j++) {
      int col = tn + wn + j * 16 + fr;
      float bv = bias[col];
      int which = col / D_MODEL;
      int hd = col % D_MODEL;
      int h = hd >> 6, d = hd & 63;
      #pragma unroll
      for (int i = 0; i < 4; i++) {
        #pragma unroll
        for (int r = 0; r < 4; r++) {
          int row = tm + wm + i * 16 + fq + r;
          int b = row >> 12, l = row & 4095;
          float v = acc[i][j][r] + bv;
          size_t hb = (size_t)b * NH + h;
          if (which == 0)      Qb[(hb * SL + l) * DHd + d] = bfc(v * QSCALE);
          else if (which == 1) Kb[(hb * SL + l) * DHd + d] = bfc(v);
          else                 Vtb[(hb * DHd + d) * SL + l] = bfc(v);
        }
      }
    }
  } else {
    float* Out = (float*)o0;
    #pragma unroll
    for (int i = 0; i < 4; i++)
      #pragma unroll
      for (int j = 0; j < 4; j++) {
        int col = tn + wn + j * 16 + fr;
        float bv = bias[col];
        #pragma unroll
        for (int r = 0; r < 4; r++) {
          int row = tm + wm + i * 16 + fq + r;
          Out[(size_t)row * N + col] = acc[i][j][r] + bv;
        }
      }
  }
}

// ---------------- flash attention (paired q-tiles, 8 waves) ----------------
// grid: 768 blocks x 512 threads. Block handles q-tiles {qi, 63-qi} of one bh:
// waves 0-3 -> tile qi (64 rows), waves 4-7 -> tile 63-qi. Shared K/V staging,
// reg-prefetch of next chunk, log2-domain softmax with defer-max.
__global__ __launch_bounds__(512) void attn_fwd(const unsigned short* __restrict__ Q,
                                                const unsigned short* __restrict__ K,
                                                const unsigned short* __restrict__ V,
                                                unsigned short* __restrict__ O) {
  // XCD-bijective swizzle: each XCD owns 3 heads (K/V set 3MB < 4MB L2)
  const int swzb = (blockIdx.x & 7) * 96 + (blockIdx.x >> 3);
  const int bh = swzb >> 5;          // 0..23
  const int qi = swzb & 31;          // 0..31
  const int tid = threadIdx.x;
  const int wave = tid >> 6, lane = tid & 63;
  const int g = wave >> 2, wv = wave & 3;
  const int fr = lane & 15, fk = lane >> 4;
  const int tq = g ? (63 - qi) : qi; // this wave-group's q-tile index
  const int q0 = tq * 64;
  const int nstage = 64 - qi;        // chunks staged = max extent of the pair

  const unsigned short* Qbh = Q + (size_t)bh * SL * DHd;
  const unsigned short* Kbh = K + (size_t)bh * SL * DHd;
  const unsigned short* Vbh = V + (size_t)bh * DHd * SL;

  __shared__ unsigned short Ks[64 * 64];    // [kv][d]  swizzled 128B rows
  __shared__ unsigned short Vs[64 * 64];    // [d][kv]  swizzled
  __shared__ unsigned short Ps[8][16 * 64]; // per-wave P, swizzled

  const unsigned short* qrow = Qbh + (size_t)(q0 + wv * 16 + fr) * DHd + fk * 8;
  bf16x8 qf0 = *(const bf16x8*)qrow;
  bf16x8 qf1 = *(const bf16x8*)(qrow + 32);

  f32x4 oacc[4] = {};
  float m_i[4], l_i[4];
  #pragma unroll
  for (int r = 0; r < 4; r++) { m_i[r] = -1e30f; l_i[r] = 0.f; }

  char* ksb = (char*)Ks;
  char* vsb = (char*)Vs;
  char* psb = (char*)(&Ps[wave][0]);
  const int srow = tid >> 3;          // 0..63 (512 threads stage full tile)
  const int sc = (tid & 7) * 16;      // byte col in 128B row
  const int ssw = (srow & 7) << 4;

  const char* kg = (const char*)Kbh + (size_t)srow * 128 + sc;  // +8192B/chunk
  const char* vg = (const char*)Vbh + (size_t)srow * (SL * 2) + sc; // +128B/chunk

  ulonglong2 kreg = *(const ulonglong2*)kg;
  ulonglong2 vreg = *(const ulonglong2*)vg;

  for (int c = 0; c < nstage; c++) {
    __syncthreads();                  // prior compute done reading LDS
    *(ulonglong2*)(ksb + srow * 128 + (sc ^ ssw)) = kreg;
    *(ulonglong2*)(vsb + srow * 128 + (sc ^ ssw)) = vreg;
    __syncthreads();
    if (c + 1 < nstage) {             // prefetch next chunk (hides under compute)
      kreg = *(const ulonglong2*)(kg + (size_t)(c + 1) * 8192);
      vreg = *(const ulonglong2*)(vg + (size_t)(c + 1) * 128);
    }

    if (c <= tq) {
      // S = Q K^T  (log2 domain; frag n: rows fk*4+r, cols n*16+fr)
      f32x4 s[4] = {};
      #pragma unroll
      for (int n = 0; n < 4; n++) {
        int r = n * 16 + fr;
        const char* kbase = ksb + r * 128;
        int sw = (r & 7) << 4;
        bf16x8 b0 = *(const bf16x8*)(kbase + ((fk * 16) ^ sw));
        bf16x8 b1 = *(const bf16x8*)(kbase + ((64 + fk * 16) ^ sw));
        s[n] = __builtin_amdgcn_mfma_f32_16x16x32_bf16(qf0, b0, s[n], 0, 0, 0);
        s[n] = __builtin_amdgcn_mfma_f32_16x16x32_bf16(qf1, b1, s[n], 0, 0, 0);
      }

      if (c == tq) {  // diagonal chunk causal mask
        #pragma unroll
        for (int n = 0; n < 4; n++)
          #pragma unroll
          for (int r = 0; r < 4; r++) {
            int qr = wv * 16 + fk * 4 + r;
            int kc = n * 16 + fr;
            if (kc > qr) s[n][r] = -1e30f;
          }
      }

      // row max (rows spread over 16 lanes sharing fk)
      float pmax[4];
      #pragma unroll
      for (int r = 0; r < 4; r++) {
        float m0 = fmaxf(fmaxf(s[0][r], s[1][r]), fmaxf(s[2][r], s[3][r]));
        m0 = fmaxf(m0, __shfl_xor(m0, 1));
        m0 = fmaxf(m0, __shfl_xor(m0, 2));
        m0 = fmaxf(m0, __shfl_xor(m0, 4));
        m0 = fmaxf(m0, __shfl_xor(m0, 8));
        pmax[r] = m0;
      }
      // defer-max: only rescale when max grew by > 12 (log2 units, P <= 2^12)
      bool grow = (pmax[0] > m_i[0] + 12.f) | (pmax[1] > m_i[1] + 12.f) |
                  (pmax[2] > m_i[2] + 12.f) | (pmax[3] > m_i[3] + 12.f);
      if (__any(grow)) {
        #pragma unroll
        for (int r = 0; r < 4; r++) {
          float nm = fmaxf(m_i[r], pmax[r]);
          float sc2 = fexp2(m_i[r] - nm);
          m_i[r] = nm;
          l_i[r] *= sc2;
          #pragma unroll
          for (int n = 0; n < 4; n++) oacc[n][r] *= sc2;
        }
      }
      #pragma unroll
      for (int n = 0; n < 4; n++)
        #pragma unroll
        for (int r = 0; r < 4; r++)
          s[n][r] = fexp2(s[n][r] - m_i[r]);
      #pragma unroll
      for (int r = 0; r < 4; r++) {
        float t = (s[0][r] + s[1][r]) + (s[2][r] + s[3][r]);
        t += __shfl_xor(t, 1);
        t += __shfl_xor(t, 2);
        t += __shfl_xor(t, 4);
        t += __shfl_xor(t, 8);
        l_i[r] += t;
      }

      // P -> wave-private LDS (bf16, swizzled): S-frag -> A-frag layout convert
      #pragma unroll
      for (int n = 0; n < 4; n++)
        #pragma unroll
        for (int r = 0; r < 4; r++) {
          int row = fk * 4 + r;
          int colb = (n * 16 + fr) * 2;
          *(unsigned short*)(psb + row * 128 + (colb ^ ((row & 7) << 4))) = bfc(s[n][r]);
        }
      asm volatile("" ::: "memory");

      // O += P @ V
      #pragma unroll
      for (int kk = 0; kk < 2; kk++) {
        int pcb = kk * 64 + fk * 16;
        bf16x8 pa = *(const bf16x8*)(psb + fr * 128 + (pcb ^ ((fr & 7) << 4)));
        #pragma unroll
        for (int n = 0; n < 4; n++) {
          int vr = n * 16 + fr;
          int vcb = kk * 64 + fk * 16;
          bf16x8 vb = *(const bf16x8*)(vsb + vr * 128 + (vcb ^ ((vr & 7) << 4)));
          oacc[n] = __builtin_amdgcn_mfma_f32_16x16x32_bf16(pa, vb, oacc[n], 0, 0, 0);
        }
      }
    }
  }

  const int b = bh / NH, h = bh % NH;
  float inv[4];
  #pragma unroll
  for (int r = 0; r < 4; r++) inv[r] = 1.0f / l_i[r];
  #pragma unroll
  for (int n = 0; n < 4; n++)
    #pragma unroll
    for (int r = 0; r < 4; r++) {
      int q = q0 + wv * 16 + fk * 4 + r;
      int d = n * 16 + fr;
      O[((size_t)b * SL + q) * D_MODEL + h * DHd + d] = bfc(oacc[n][r] * inv[r]);
    }
}

// ---------------- launch ----------------
extern "C" void kernel_launch(void* const* d_in, const int* in_sizes, int n_in,
                              void* d_out, int out_size, void* d_ws, size_t ws_size,
                              hipStream_t stream) {
  (void)in_sizes; (void)n_in; (void)out_size; (void)ws_size;
  const float* x     = (const float*)d_in[0];
  const float* w_qkv = (const float*)d_in[1];
  const float* b_qkv = (const float*)d_in[2];
  const float* w_out = (const float*)d_in[3];
  const float* b_out = (const float*)d_in[4];
  float* out = (float*)d_out;

  unsigned short* p = (unsigned short*)d_ws;
  unsigned short* xb    = p; p += (size_t)BLr * D_MODEL;
  unsigned short* wqkvT = p; p += (size_t)N3 * D_MODEL;
  unsigned short* woutT = p; p += (size_t)D_MODEL * D_MODEL;
  unsigned short* Qb    = p; p += (size_t)NB * NH * SL * DHd;  // [b,h,l,d] scaled by log2e/8
  unsigned short* Kb    = p; p += (size_t)NB * NH * SL * DHd;  // [b,h,l,d]
  unsigned short* Vtb   = p; p += (size_t)NB * NH * SL * DHd;  // [b,h,d,l]
  unsigned short* Ob    = p;                                   // [b*l][768] bf16

  cast_f32_bf16<<<(BLr * D_MODEL / 4 + 255) / 256, 256, 0, stream>>>(x, xb, BLr * D_MODEL / 4);
  transpose_cast<<<dim3(N3 / 32, D_MODEL / 32), 256, 0, stream>>>(w_qkv, wqkvT, D_MODEL, N3);
  transpose_cast<<<dim3(D_MODEL / 32, D_MODEL / 32), 256, 0, stream>>>(w_out, woutT, D_MODEL, D_MODEL);
  gemm_bf16<0><<<dim3(BLr / 128, N3 / 128), 256, 0, stream>>>(xb, wqkvT, b_qkv, Qb, Kb, Vtb,
                                                              BLr, N3, D_MODEL);
  attn_fwd<<<768, 512, 0, stream>>>(Qb, Kb, Vtb, Ob);
  gemm_bf16<1><<<dim3(BLr / 128, D_MODEL / 128), 256, 0, stream>>>(Ob, woutT, b_out, out,
                                                                   nullptr, nullptr,
                                                                   BLr, D_MODEL, D_MODEL);
}

// Round 3
// 210.210 us; speedup vs baseline: 1.6713x; 1.2229x over previous
//
#include <hip/hip_runtime.h>
#include <hip/hip_bf16.h>

#define D_MODEL 768
#define NH 12
#define DHd 64
#define NB 2
#define SL 4096
#define BLr (NB*SL)      // 8192 rows
#define N3 (3*D_MODEL)   // 2304
#define QSCALE 0.18033688011112042f   // 0.125 * log2(e): softmax in log2 domain

typedef __bf16 bf16x8 __attribute__((ext_vector_type(8)));
typedef float f32x4 __attribute__((ext_vector_type(4)));
typedef float f32x16 __attribute__((ext_vector_type(16)));
typedef unsigned int u32x4 __attribute__((ext_vector_type(4)));

__device__ __forceinline__ unsigned short f2bf(float f) {
  unsigned int u = __float_as_uint(f);
  u = (u + 0x7FFFu + ((u >> 16) & 1u)) >> 16;
  return (unsigned short)u;
}
__device__ __forceinline__ unsigned short bfc(float f) {
  __bf16 h = (__bf16)f;
  return __builtin_bit_cast(unsigned short, h);
}
__device__ __forceinline__ float fexp2(float x) {
  float r; asm("v_exp_f32 %0, %1" : "=v"(r) : "v"(x)); return r;
}
__device__ __forceinline__ unsigned int pk2(float lo, float hi2) {
  return ((unsigned int)bfc(hi2) << 16) | (unsigned int)bfc(lo);
}
__device__ __forceinline__ float vmax16(const f32x16& v) {
  float a = fmaxf(fmaxf(fmaxf(v[0],v[1]),fmaxf(v[2],v[3])),
                  fmaxf(fmaxf(v[4],v[5]),fmaxf(v[6],v[7])));
  float b = fmaxf(fmaxf(fmaxf(v[8],v[9]),fmaxf(v[10],v[11])),
                  fmaxf(fmaxf(v[12],v[13]),fmaxf(v[14],v[15])));
  return fmaxf(a,b);
}
__device__ __forceinline__ float vsum16(const f32x16& v) {
  float a = (v[0]+v[1])+(v[2]+v[3]);
  float b = (v[4]+v[5])+(v[6]+v[7]);
  float c = (v[8]+v[9])+(v[10]+v[11]);
  float d = (v[12]+v[13])+(v[14]+v[15]);
  return (a+b)+(c+d);
}

// ---------------- prep kernels ----------------
__global__ __launch_bounds__(256) void cast_f32_bf16(const float* __restrict__ in,
                                                     unsigned short* __restrict__ out, int n4) {
  int i = blockIdx.x * 256 + threadIdx.x;
  if (i >= n4) return;
  float4 v = reinterpret_cast<const float4*>(in)[i];
  ushort4 o;
  o.x = f2bf(v.x); o.y = f2bf(v.y); o.z = f2bf(v.z); o.w = f2bf(v.w);
  reinterpret_cast<ushort4*>(out)[i] = o;
}

__global__ __launch_bounds__(256) void transpose_cast(const float* __restrict__ in,
                                                      unsigned short* __restrict__ out,
                                                      int R, int C) {
  __shared__ float t[32][33];
  int c0 = blockIdx.x * 32, r0 = blockIdx.y * 32;
  int tx = threadIdx.x & 31, ty = threadIdx.x >> 5;
  #pragma unroll
  for (int i = 0; i < 32; i += 8) t[ty + i][tx] = in[(size_t)(r0 + ty + i) * C + c0 + tx];
  __syncthreads();
  #pragma unroll
  for (int i = 0; i < 32; i += 8) out[(size_t)(c0 + ty + i) * R + r0 + tx] = f2bf(t[tx][ty + i]);
}

// ---------------- bf16 GEMM: C = A(MxK) * Bt(NxK)^T + bias ----------------
template<int MODE>
__global__ __launch_bounds__(256) void gemm_bf16(const unsigned short* __restrict__ A,
                                                 const unsigned short* __restrict__ Bt,
                                                 const float* __restrict__ bias,
                                                 void* __restrict__ o0, void* __restrict__ o1,
                                                 void* __restrict__ o2,
                                                 int M, int N, int Kdim) {
  constexpr int LDT = 40;
  __shared__ unsigned short As[128 * LDT];
  __shared__ unsigned short Bs[128 * LDT];
  const int tid = threadIdx.x;
  const int lane = tid & 63, wave = tid >> 6;
  const int tm = blockIdx.x * 128, tn = blockIdx.y * 128;
  const int wm = (wave >> 1) * 64, wn = (wave & 1) * 64;
  const int fr = lane & 15, fk8 = (lane >> 4) * 8;
  const int srow = tid >> 2, scol = (tid & 3) * 8;

  f32x4 acc[4][4] = {};

  const unsigned short* Arow0 = A + (size_t)(tm + srow) * Kdim + scol;
  const unsigned short* Arow1 = A + (size_t)(tm + 64 + srow) * Kdim + scol;
  const unsigned short* Brow0 = Bt + (size_t)(tn + srow) * Kdim + scol;
  const unsigned short* Brow1 = Bt + (size_t)(tn + 64 + srow) * Kdim + scol;

  for (int k0 = 0; k0 < Kdim; k0 += 32) {
    ulonglong2 a0 = *(const ulonglong2*)(Arow0 + k0);
    ulonglong2 a1 = *(const ulonglong2*)(Arow1 + k0);
    ulonglong2 b0 = *(const ulonglong2*)(Brow0 + k0);
    ulonglong2 b1 = *(const ulonglong2*)(Brow1 + k0);
    __syncthreads();
    *(ulonglong2*)(As + srow * LDT + scol) = a0;
    *(ulonglong2*)(As + (64 + srow) * LDT + scol) = a1;
    *(ulonglong2*)(Bs + srow * LDT + scol) = b0;
    *(ulonglong2*)(Bs + (64 + srow) * LDT + scol) = b1;
    __syncthreads();

    bf16x8 af[4], bfr[4];
    #pragma unroll
    for (int i = 0; i < 4; i++) {
      af[i]  = *(const bf16x8*)(As + (wm + i * 16 + fr) * LDT + fk8);
      bfr[i] = *(const bf16x8*)(Bs + (wn + i * 16 + fr) * LDT + fk8);
    }
    #pragma unroll
    for (int i = 0; i < 4; i++)
      #pragma unroll
      for (int j = 0; j < 4; j++)
        acc[i][j] = __builtin_amdgcn_mfma_f32_16x16x32_bf16(af[i], bfr[j], acc[i][j], 0, 0, 0);
  }

  const int fq = (lane >> 4) * 4;
  if constexpr (MODE == 0) {
    unsigned short* Qb  = (unsigned short*)o0;
    unsigned short* Kb  = (unsigned short*)o1;
    unsigned short* Vtb = (unsigned short*)o2;
    #pragma unroll
    for (int j = 0; j < 4; j++) {
      int col = tn + wn + j * 16 + fr;
      float bv = bias[col];
      int which = col / D_MODEL;
      int hd = col % D_MODEL;
      int h = hd >> 6, d = hd & 63;
      #pragma unroll
      for (int i = 0; i < 4; i++) {
        #pragma unroll
        for (int r = 0; r < 4; r++) {
          int row = tm + wm + i * 16 + fq + r;
          int b = row >> 12, l = row & 4095;
          float v = acc[i][j][r] + bv;
          size_t hb = (size_t)b * NH + h;
          if (which == 0)      Qb[(hb * SL + l) * DHd + d] = bfc(v * QSCALE);
          else if (which == 1) Kb[(hb * SL + l) * DHd + d] = bfc(v);
          else                 Vtb[(hb * DHd + d) * SL + l] = bfc(v);
        }
      }
    }
  } else {
    float* Out = (float*)o0;
    #pragma unroll
    for (int i = 0; i < 4; i++)
      #pragma unroll
      for (int j = 0; j < 4; j++) {
        int col = tn + wn + j * 16 + fr;
        float bv = bias[col];
        #pragma unroll
        for (int r = 0; r < 4; r++) {
          int row = tm + wm + i * 16 + fq + r;
          Out[(size_t)row * N + col] = acc[i][j][r] + bv;
        }
      }
  }
}

// ---------------- flash attention: swapped-QK 32x32, in-register softmax ----
// grid 768 x 256thr (4 waves). Block = q-tile pair {qi, 63-qi} of one bh.
// wave w: group g=w>>1 -> tile (g? 63-qi : qi), sub=w&1 -> 32-row half.
// Per wave QBLK=32 q-rows; KVBLK=64 staged in LDS (K[64][64], Vt[64][64]).
// S^T = mfma(K, Q): lane owns q=lane&31; kv regs quad-pattern +4*(lane>>5).
#define PVSTEP(P, B, KS) do {                                              \
    unsigned int u0 = pk2(P[(B)+0], P[(B)+1]);                             \
    unsigned int u1 = pk2(P[(B)+2], P[(B)+3]);                             \
    unsigned int u2 = pk2(P[(B)+4], P[(B)+5]);                             \
    unsigned int u3 = pk2(P[(B)+6], P[(B)+7]);                             \
    unsigned int e0 = __shfl_xor(hi ? u0 : u2, 32);                        \
    unsigned int e1 = __shfl_xor(hi ? u1 : u3, 32);                        \
    u32x4 w;                                                               \
    w[0] = hi ? e0 : u0; w[1] = hi ? e1 : u1;                              \
    w[2] = hi ? u2 : e0; w[3] = hi ? u3 : e1;                              \
    bf16x8 pa = __builtin_bit_cast(bf16x8, w);                             \
    int bc = (32*(KS) + 16*hi) ^ vsw;                                      \
    bf16x8 vb0 = *(const bf16x8*)(vsb + l31*128 + bc);                     \
    oacc0 = __builtin_amdgcn_mfma_f32_32x32x16_bf16(pa, vb0, oacc0, 0,0,0);\
    bf16x8 vb1 = *(const bf16x8*)(vsb + (32+l31)*128 + bc);                \
    oacc1 = __builtin_amdgcn_mfma_f32_32x32x16_bf16(pa, vb1, oacc1, 0,0,0);\
  } while(0)

__global__ __launch_bounds__(256, 3) void attn_fwd(const unsigned short* __restrict__ Q,
                                                   const unsigned short* __restrict__ K,
                                                   const unsigned short* __restrict__ V,
                                                   unsigned short* __restrict__ O) {
  const int swzb = (blockIdx.x & 7) * 96 + (blockIdx.x >> 3);
  const int bh = swzb >> 5;          // 0..23
  const int qi = swzb & 31;          // 0..31
  const int tid = threadIdx.x;
  const int wave = tid >> 6, lane = tid & 63;
  const int g = wave >> 1, sub = wave & 1;
  const int l31 = lane & 31, hi = lane >> 5;
  const int tq = g ? (63 - qi) : qi;
  const int q0w = tq * 64 + sub * 32;      // wave's 32 q-rows start
  const int nstage = 64 - qi;

  const unsigned short* Qbh = Q + (size_t)bh * SL * DHd;
  const unsigned short* Kbh = K + (size_t)bh * SL * DHd;
  const unsigned short* Vbh = V + (size_t)bh * DHd * SL;

  __shared__ unsigned short Ks[64 * 64];   // [kv][d] swizzled 128B rows
  __shared__ unsigned short Vs[64 * 64];   // [d][kv] swizzled

  // Q fragments: B-frag f: q=l31, d = 16f + 8*hi + j
  const char* qp = (const char*)Qbh + (size_t)(q0w + l31) * 128 + 16 * hi;
  bf16x8 qf0 = *(const bf16x8*)(qp);
  bf16x8 qf1 = *(const bf16x8*)(qp + 32);
  bf16x8 qf2 = *(const bf16x8*)(qp + 64);
  bf16x8 qf3 = *(const bf16x8*)(qp + 96);

  f32x16 oacc0 = {}, oacc1 = {};
  float m_i = -1e30f, l_i = 0.f;

  char* ksb = (char*)Ks;
  char* vsb = (char*)Vs;
  const int srow = tid >> 2;             // 0..63
  const int scB = (tid & 3) * 32;        // byte col {0,32,64,96}
  const int ssw = (srow & 7) << 4;
  const int vsw = (l31 & 7) << 4;        // V/K read swizzle (row&7 same for +32)

  const char* kgp = (const char*)Kbh + (size_t)srow * 128 + scB;
  const char* vgp = (const char*)Vbh + (size_t)srow * (SL * 2) + scB;

  ulonglong2 kr0 = *(const ulonglong2*)(kgp);
  ulonglong2 kr1 = *(const ulonglong2*)(kgp + 16);
  ulonglong2 vr0 = *(const ulonglong2*)(vgp);
  ulonglong2 vr1 = *(const ulonglong2*)(vgp + 16);

  for (int c = 0; c < nstage; c++) {
    __syncthreads();
    *(ulonglong2*)(ksb + srow * 128 + (scB ^ ssw)) = kr0;
    *(ulonglong2*)(ksb + srow * 128 + ((scB + 16) ^ ssw)) = kr1;
    *(ulonglong2*)(vsb + srow * 128 + (scB ^ ssw)) = vr0;
    *(ulonglong2*)(vsb + srow * 128 + ((scB + 16) ^ ssw)) = vr1;
    __syncthreads();
    if (c + 1 < nstage) {
      kr0 = *(const ulonglong2*)(kgp + (size_t)(c + 1) * 8192);
      kr1 = *(const ulonglong2*)(kgp + (size_t)(c + 1) * 8192 + 16);
      vr0 = *(const ulonglong2*)(vgp + (size_t)(c + 1) * 128);
      vr1 = *(const ulonglong2*)(vgp + (size_t)(c + 1) * 128 + 16);
    }

    if (c <= tq) {
      const int k0 = c * 64;
      const bool g1act = (k0 + 32 <= q0w);   // grp1 (kv k0+32..k0+63) not fully masked
      f32x16 s0 = {}, s1 = {};

      __builtin_amdgcn_s_setprio(1);
      {  // grp0: kv rows k0 + l31
        const char* kr = ksb + l31 * 128;
        bf16x8 a0 = *(const bf16x8*)(kr + ((16 * hi) ^ vsw));
        s0 = __builtin_amdgcn_mfma_f32_32x32x16_bf16(a0, qf0, s0, 0, 0, 0);
        bf16x8 a1 = *(const bf16x8*)(kr + ((32 + 16 * hi) ^ vsw));
        s0 = __builtin_amdgcn_mfma_f32_32x32x16_bf16(a1, qf1, s0, 0, 0, 0);
        bf16x8 a2 = *(const bf16x8*)(kr + ((64 + 16 * hi) ^ vsw));
        s0 = __builtin_amdgcn_mfma_f32_32x32x16_bf16(a2, qf2, s0, 0, 0, 0);
        bf16x8 a3 = *(const bf16x8*)(kr + ((96 + 16 * hi) ^ vsw));
        s0 = __builtin_amdgcn_mfma_f32_32x32x16_bf16(a3, qf3, s0, 0, 0, 0);
      }
      if (g1act) {
        const char* kr = ksb + (32 + l31) * 128;
        bf16x8 a0 = *(const bf16x8*)(kr + ((16 * hi) ^ vsw));
        s1 = __builtin_amdgcn_mfma_f32_32x32x16_bf16(a0, qf0, s1, 0, 0, 0);
        bf16x8 a1 = *(const bf16x8*)(kr + ((32 + 16 * hi) ^ vsw));
        s1 = __builtin_amdgcn_mfma_f32_32x32x16_bf16(a1, qf1, s1, 0, 0, 0);
        bf16x8 a2 = *(const bf16x8*)(kr + ((64 + 16 * hi) ^ vsw));
        s1 = __builtin_amdgcn_mfma_f32_32x32x16_bf16(a2, qf2, s1, 0, 0, 0);
        bf16x8 a3 = *(const bf16x8*)(kr + ((96 + 16 * hi) ^ vsw));
        s1 = __builtin_amdgcn_mfma_f32_32x32x16_bf16(a3, qf3, s1, 0, 0, 0);
      }
      __builtin_amdgcn_s_setprio(0);

      // causal mask: 32-block diagonal when kv_base == q0w
      if (k0 == q0w) {
        #pragma unroll
        for (int r = 0; r < 16; r++) {
          int kvo = (r & 3) + 8 * (r >> 2) + 4 * hi;
          if (kvo > l31) s0[r] = -1e30f;
        }
      }
      if (g1act && (k0 + 32 == q0w)) {
        #pragma unroll
        for (int r = 0; r < 16; r++) {
          int kvo = (r & 3) + 8 * (r >> 2) + 4 * hi;
          if (kvo > l31) s1[r] = -1e30f;
        }
      }

      // online softmax (q = l31 per lane; partner lane^32 holds other half of row)
      float pm = vmax16(s0);
      if (g1act) pm = fmaxf(pm, vmax16(s1));
      pm = fmaxf(pm, __shfl_xor(pm, 32));
      if (__any(pm > m_i + 10.f)) {          // defer-max THR=10 (log2 units)
        float nm = fmaxf(m_i, pm);
        float sc = fexp2(m_i - nm);
        m_i = nm; l_i *= sc;
        #pragma unroll
        for (int r = 0; r < 16; r++) {
          float scr = __shfl(sc, (r & 3) + 8 * (r >> 2) + 4 * hi);
          oacc0[r] *= scr; oacc1[r] *= scr;
        }
      }
      #pragma unroll
      for (int r = 0; r < 16; r++) s0[r] = fexp2(s0[r] - m_i);
      float ts = vsum16(s0);
      if (g1act) {
        #pragma unroll
        for (int r = 0; r < 16; r++) s1[r] = fexp2(s1[r] - m_i);
        ts += vsum16(s1);
      }
      ts += __shfl_xor(ts, 32);
      l_i += ts;

      // PV: P(in-register) @ V, per 16-kv slot
      __builtin_amdgcn_s_setprio(1);
      PVSTEP(s0, 0, 0);
      PVSTEP(s0, 8, 1);
      if (g1act) {
        PVSTEP(s1, 0, 2);
        PVSTEP(s1, 8, 3);
      }
      __builtin_amdgcn_s_setprio(0);
    }
  }

  const int b = bh / NH, h = bh % NH;
  #pragma unroll
  for (int r = 0; r < 16; r++) {
    int qo = (r & 3) + 8 * (r >> 2) + 4 * hi;
    float lq = __shfl(l_i, qo);
    float inv = 1.0f / lq;
    size_t base = ((size_t)b * SL + q0w + qo) * D_MODEL + h * DHd;
    O[base + l31]      = bfc(oacc0[r] * inv);
    O[base + 32 + l31] = bfc(oacc1[r] * inv);
  }
}

// ---------------- launch ----------------
extern "C" void kernel_launch(void* const* d_in, const int* in_sizes, int n_in,
                              void* d_out, int out_size, void* d_ws, size_t ws_size,
                              hipStream_t stream) {
  (void)in_sizes; (void)n_in; (void)out_size; (void)ws_size;
  const float* x     = (const float*)d_in[0];
  const float* w_qkv = (const float*)d_in[1];
  const float* b_qkv = (const float*)d_in[2];
  const float* w_out = (const float*)d_in[3];
  const float* b_out = (const float*)d_in[4];
  float* out = (float*)d_out;

  unsigned short* p = (unsigned short*)d_ws;
  unsigned short* xb    = p; p += (size_t)BLr * D_MODEL;
  unsigned short* wqkvT = p; p += (size_t)N3 * D_MODEL;
  unsigned short* woutT = p; p += (size_t)D_MODEL * D_MODEL;
  unsigned short* Qb    = p; p += (size_t)NB * NH * SL * DHd;  // [b,h,l,d] * log2e/8
  unsigned short* Kb    = p; p += (size_t)NB * NH * SL * DHd;  // [b,h,l,d]
  unsigned short* Vtb   = p; p += (size_t)NB * NH * SL * DHd;  // [b,h,d,l]
  unsigned short* Ob    = p;                                   // [b*l][768] bf16

  cast_f32_bf16<<<(BLr * D_MODEL / 4 + 255) / 256, 256, 0, stream>>>(x, xb, BLr * D_MODEL / 4);
  transpose_cast<<<dim3(N3 / 32, D_MODEL / 32), 256, 0, stream>>>(w_qkv, wqkvT, D_MODEL, N3);
  transpose_cast<<<dim3(D_MODEL / 32, D_MODEL / 32), 256, 0, stream>>>(w_out, woutT, D_MODEL, D_MODEL);
  gemm_bf16<0><<<dim3(BLr / 128, N3 / 128), 256, 0, stream>>>(xb, wqkvT, b_qkv, Qb, Kb, Vtb,
                                                              BLr, N3, D_MODEL);
  attn_fwd<<<768, 256, 0, stream>>>(Qb, Kb, Vtb, Ob);
  gemm_bf16<1><<<dim3(BLr / 128, D_MODEL / 128), 256, 0, stream>>>(Ob, woutT, b_out, out,
                                                                   nullptr, nullptr,
                                                                   BLr, D_MODEL, D_MODEL);
}